// Round 9
// baseline (1555.589 us; speedup 1.0000x reference)
//
#include <hip/hip_runtime.h>

#define NB 512
#define NT 256
#define NI 32
#define NH 128
#define NG 512

typedef __attribute__((ext_vector_type(8))) short bf16x8;
typedef __attribute__((ext_vector_type(4))) float f32x4;

__device__ __forceinline__ float fsig(float x) { return 1.0f / (1.0f + __expf(-x)); }
__device__ __forceinline__ float ftanh(float x) {
    float ax = fabsf(x);
    float e  = __expf(-2.0f * ax);
    float t  = (1.0f - e) / (1.0f + e);
    return copysignf(t, x);
}
__device__ __forceinline__ unsigned short f2bf_rne(float f) {
    unsigned u = __float_as_uint(f);
    return (unsigned short)((u + 0x7FFFu + ((u >> 16) & 1u)) >> 16);
}
__device__ __forceinline__ void split2(float a, float b, unsigned& hi, unsigned& lo) {
    unsigned short ha = f2bf_rne(a), hb = f2bf_rne(b);
    float ra = a - __uint_as_float((unsigned)ha << 16);
    float rb = b - __uint_as_float((unsigned)hb << 16);
    hi = (unsigned)ha | ((unsigned)hb << 16);
    lo = (unsigned)f2bf_rne(ra) | ((unsigned)f2bf_rne(rb) << 16);
}
__device__ __forceinline__ bf16x8 u4bf(uint4 u) {
    union { uint4 u; bf16x8 v; } c; c.u = u; return c.v;
}
#define MFMA16(accv, av, bv) \
    accv = __builtin_amdgcn_mfma_f32_16x16x32_bf16(av, bv, accv, 0, 0, 0)

// ---------------------------------------------------------------------------
// MFMA LSTM recurrence. 32 blocks x 512 threads; block owns 16 batches.
// gates[16 batch][512 gate] = xg[b,t,:] + h @ w_hh^T via mfma_f32_16x16x32_bf16
// (split-bf16, 3 terms: ah*wh + al*wh + ah*wl — same 2^-17 scheme R8 verified).
// Wave wv owns n-tiles {wv, 8+wv, 16+wv, 24+wv} = gate types i,f,g,o for
// j in [16wv,16wv+16): after MFMA each lane holds all 4 gate types for its
// 4 (batch=quad*4+reg, j=16wv+ml) pairs IN REGISTERS -> c/h update fully
// in-wave, c never leaves VGPRs, NO act LDS round-trip, ONE barrier/step.
// Weights: w_hi regs (16 frags = 64 VGPRs), w_lo LDS 128KB (dense 1KB/frag,
// conflict-free). h stored in LDS as bf16 hi/lo limbs (A-op layout, dbuf).
// xg folds into the accumulator init (D-layout scalar loads).
// Reg ledger ~118 < 128 cap (R1-R6 ledger: stay >=10 under cap or spill).
// ---------------------------------------------------------------------------
template<bool WRITE_H>
__global__ __launch_bounds__(512, 1)
void recur(const float* __restrict__ xg,    // [NB*Tc][NG] rows = b*Tc+tl
           const float* __restrict__ w_hh,  // [NG][NH]
           float* __restrict__ hout,        // WRITE_H: rows b*Tc+tl, [NH]
           float* __restrict__ h_state, float* __restrict__ c_state, // [NB][NH]
           int Tc, int first)
{
    __shared__ __align__(16) unsigned short Wl[128][64][8];   // 131072 B
    __shared__ __align__(16) unsigned short Hh[2][4][64][8];  // 8192 B
    __shared__ __align__(16) unsigned short Hl[2][4][64][8];  // 8192 B

    const int tid  = threadIdx.x;
    const int wv   = tid >> 6;          // 0..7
    const int lane = tid & 63;
    const int quad = lane >> 4;         // 0..3
    const int ml   = lane & 15;         // 0..15
    const int bk   = blockIdx.x;        // batches [16bk, 16bk+16)
    const int j    = 16 * wv + ml;      // hidden column this lane updates
    const int qp   = j >> 5;            // h-limb write coords (A-op layout)
    const int qdp  = (j & 31) >> 3;
    const int jj   = j & 7;
    const int lidx = ml * 4 + quad;     // dense lane index for 16B frags

    // ---- stage weights: hi -> regs, lo -> LDS ----
    bf16x8 wh[4][4];
#pragma unroll
    for (int t = 0; t < 4; ++t) {
#pragma unroll
        for (int q = 0; q < 4; ++q) {
            int n = (t * 8 + wv) * 16 + ml;
            const float* s = w_hh + (size_t)n * NH + q * 32 + quad * 8;
            float4 v0 = *(const float4*)s;
            float4 v1 = *(const float4*)(s + 4);
            uint4 H, L;
            split2(v0.x, v0.y, H.x, L.x); split2(v0.z, v0.w, H.y, L.y);
            split2(v1.x, v1.y, H.z, L.z); split2(v1.z, v1.w, H.w, L.w);
            wh[t][q] = u4bf(H);
            *(uint4*)&Wl[(t * 8 + wv) * 4 + q][lidx][0] = L;
        }
    }

    // ---- initial c/h ----
    float cr[4], hk[4];
#pragma unroll
    for (int r = 0; r < 4; ++r) {
        int m = quad * 4 + r;
        float h = 0.f, c = 0.f;
        if (!first) {
            h = h_state[(size_t)(bk * 16 + m) * NH + j];
            c = c_state[(size_t)(bk * 16 + m) * NH + j];
        }
        cr[r] = c; hk[r] = h;
        unsigned short hi = f2bf_rne(h);
        Hh[0][qp][m * 4 + qdp][jj] = hi;
        Hl[0][qp][m * 4 + qdp][jj] = f2bf_rne(h - __uint_as_float((unsigned)hi << 16));
    }
    __syncthreads();

    const size_t rs = (size_t)Tc * NG;
    const size_t rowb0 = ((size_t)(bk * 16 + quad * 4) * Tc) * NG + j;

    for (int tl = 0; tl < Tc; ++tl) {
        const int buf = tl & 1, nbuf = buf ^ 1;

        // acc init = xg (gate pre-acts with biases), D-layout:
        // acc[t][r] = xg[row = (bk*16 + quad*4 + r)*Tc + tl][t*128 + j]
        f32x4 acc[4];
        const size_t rowb = rowb0 + (size_t)tl * NG;
#pragma unroll
        for (int t = 0; t < 4; ++t)
#pragma unroll
            for (int r = 0; r < 4; ++r)
                acc[t][r] = xg[rowb + (size_t)r * rs + t * 128];

        // 48 MFMAs: 4 k-chunks x 4 gate types x 3 split terms
#pragma unroll
        for (int q = 0; q < 4; ++q) {
            bf16x8 ah = *(const bf16x8*)&Hh[buf][q][lidx][0];
            bf16x8 al = *(const bf16x8*)&Hl[buf][q][lidx][0];
#pragma unroll
            for (int t = 0; t < 4; ++t) {
                bf16x8 wlv = *(const bf16x8*)&Wl[(t * 8 + wv) * 4 + q][lidx][0];
                MFMA16(acc[t], ah, wh[t][q]);
                MFMA16(acc[t], al, wh[t][q]);
                MFMA16(acc[t], ah, wlv);
            }
        }

        // in-register gate activation + c/h update (lane owns 4 (m,j) pairs)
#pragma unroll
        for (int r = 0; r < 4; ++r) {
            float gi = fsig (acc[0][r]);
            float gf = fsig (acc[1][r]);
            float gg = ftanh(acc[2][r]);
            float go = fsig (acc[3][r]);
            cr[r] = gf * cr[r] + gi * gg;
            float hn = go * ftanh(cr[r]);
            hk[r] = hn;
            int m = quad * 4 + r;
            unsigned short hi = f2bf_rne(hn);
            Hh[nbuf][qp][m * 4 + qdp][jj] = hi;
            Hl[nbuf][qp][m * 4 + qdp][jj] =
                f2bf_rne(hn - __uint_as_float((unsigned)hi << 16));
            if (WRITE_H)
                hout[((size_t)(bk * 16 + m) * Tc + tl) * NH + j] = hn;
        }
        __syncthreads();   // h(nbuf) visible to all waves for step tl+1
    }

#pragma unroll
    for (int r = 0; r < 4; ++r) {
        int m = quad * 4 + r;
        h_state[(size_t)(bk * 16 + m) * NH + j] = hk[r];
        c_state[(size_t)(bk * 16 + m) * NH + j] = cr[r];
    }
}

// ---------------------------------------------------------------------------
// Split-bf16 MFMA GEMM (UNCHANGED from R8 — verified): C = A @ Bw^T + bias.
// ---------------------------------------------------------------------------
template<int KP, bool SLICED>
__global__ __launch_bounds__(256)
void gemm_mfma(const float* __restrict__ A,
               const float* __restrict__ Bw,
               const float* __restrict__ bi, const float* __restrict__ bh,
               float* __restrict__ C, int t0, int tcShift)
{
    constexpr int K = KP * 32;
    __shared__ __align__(16) unsigned short Ah[4][128][8], Al[4][128][8];
    __shared__ __align__(16) unsigned short Bh[4][64][8],  Bl[4][64][8];
    const int tid  = threadIdx.x;
    const int n0   = blockIdx.x * 64;
    const int m0   = blockIdx.y * 128;
    const int wv   = tid >> 6;
    const int lane = tid & 63;
    const int quad = lane >> 4, ml = lane & 15;

    f32x4 acc[2][4] = {};
    float bias[4];
#pragma unroll
    for (int nt = 0; nt < 4; ++nt) {
        int n = n0 + nt * 16 + ml;
        bias[nt] = bi[n] + bh[n];
    }

    for (int kp = 0; kp < KP; ++kp) {
        if (kp) __syncthreads();
#pragma unroll
        for (int r = 0; r < 2; ++r) {
            int u = tid + 256 * r;
            int m = u >> 2, ck = u & 3;
            size_t abase;
            if (SLICED) {
                int mg = m0 + m;
                int b  = mg >> tcShift, tl = mg & ((1 << tcShift) - 1);
                abase = ((size_t)b * NT + (t0 + tl)) * K;
            } else {
                abase = (size_t)(m0 + m) * K;
            }
            const float* s = A + abase + kp * 32 + ck * 8;
            float4 v0 = *(const float4*)s;
            float4 v1 = *(const float4*)(s + 4);
            uint4 H, L;
            split2(v0.x, v0.y, H.x, L.x); split2(v0.z, v0.w, H.y, L.y);
            split2(v1.x, v1.y, H.z, L.z); split2(v1.z, v1.w, H.w, L.w);
            *(uint4*)&Ah[ck][m][0] = H;
            *(uint4*)&Al[ck][m][0] = L;
        }
        {
            int n = tid >> 2, ck = tid & 3;
            const float* s = Bw + (size_t)(n0 + n) * K + kp * 32 + ck * 8;
            float4 v0 = *(const float4*)s;
            float4 v1 = *(const float4*)(s + 4);
            uint4 H, L;
            split2(v0.x, v0.y, H.x, L.x); split2(v0.z, v0.w, H.y, L.y);
            split2(v1.x, v1.y, H.z, L.z); split2(v1.z, v1.w, H.w, L.w);
            *(uint4*)&Bh[ck][n][0] = H;
            *(uint4*)&Bl[ck][n][0] = L;
        }
        __syncthreads();

        bf16x8 ah0 = *(const bf16x8*)&Ah[quad][(2 * wv + 0) * 16 + ml][0];
        bf16x8 al0 = *(const bf16x8*)&Al[quad][(2 * wv + 0) * 16 + ml][0];
        bf16x8 ah1 = *(const bf16x8*)&Ah[quad][(2 * wv + 1) * 16 + ml][0];
        bf16x8 al1 = *(const bf16x8*)&Al[quad][(2 * wv + 1) * 16 + ml][0];
#pragma unroll
        for (int nt = 0; nt < 4; ++nt) {
            bf16x8 bhv = *(const bf16x8*)&Bh[quad][nt * 16 + ml][0];
            bf16x8 blv = *(const bf16x8*)&Bl[quad][nt * 16 + ml][0];
            MFMA16(acc[0][nt], ah0, bhv);
            MFMA16(acc[0][nt], ah0, blv);
            MFMA16(acc[0][nt], al0, bhv);
            MFMA16(acc[1][nt], ah1, bhv);
            MFMA16(acc[1][nt], ah1, blv);
            MFMA16(acc[1][nt], al1, bhv);
        }
    }

#pragma unroll
    for (int mt = 0; mt < 2; ++mt)
#pragma unroll
        for (int nt = 0; nt < 4; ++nt)
#pragma unroll
            for (int reg = 0; reg < 4; ++reg) {
                int m = m0 + (2 * wv + mt) * 16 + quad * 4 + reg;
                int n = n0 + nt * 16 + ml;
                C[(size_t)m * NG + n] = acc[mt][nt][reg] + bias[nt];
            }
}

// ---------------------------------------------------------------------------
// out[b] = fc2_w . relu(fc1_w @ h1_last[b] + fc1_b) + fc2_b
// ---------------------------------------------------------------------------
__global__ void fc_head(const float* __restrict__ h1,
                        const float* __restrict__ fc1w, const float* __restrict__ fc1b,
                        const float* __restrict__ fc2w, const float* __restrict__ fc2b,
                        float* __restrict__ out)
{
    int b = blockIdx.x, j = threadIdx.x;
    const float4* wr = (const float4*)(fc1w + (size_t)j * NH);
    const float4* hv = (const float4*)(h1 + (size_t)b * NH);
    float acc = fc1b[j];
#pragma unroll
    for (int q = 0; q < 32; ++q) {
        float4 w = wr[q], h = hv[q];
        acc += w.x * h.x + w.y * h.y + w.z * h.z + w.w * h.w;
    }
    float z = fmaxf(acc, 0.0f);
    float p = fc2w[j] * z;
#pragma unroll
    for (int off = 32; off > 0; off >>= 1) p += __shfl_down(p, off);
    if (j == 0) out[b] = p + fc2b[0];
}

extern "C" void kernel_launch(void* const* d_in, const int* in_sizes, int n_in,
                              void* d_out, int out_size, void* d_ws, size_t ws_size,
                              hipStream_t stream)
{
    const float* x     = (const float*)d_in[0];
    const float* w_ih0 = (const float*)d_in[1];
    const float* w_hh0 = (const float*)d_in[2];
    const float* b_ih0 = (const float*)d_in[3];
    const float* b_hh0 = (const float*)d_in[4];
    const float* w_ih1 = (const float*)d_in[5];
    const float* w_hh1 = (const float*)d_in[6];
    const float* b_ih1 = (const float*)d_in[7];
    const float* b_hh1 = (const float*)d_in[8];
    const float* fc1w  = (const float*)d_in[9];
    const float* fc1b  = (const float*)d_in[10];
    const float* fc2w  = (const float*)d_in[11];
    const float* fc2b  = (const float*)d_in[12];
    float* out = (float*)d_out;
    float* ws  = (float*)d_ws;

    int Tc = 1;
    for (int cand = 256; cand >= 1; cand >>= 1) {
        size_t need = 4ull * ((size_t)NB * cand * (NG + NH) + 4ull * NB * NH);
        if (need <= ws_size) { Tc = cand; break; }
    }
    int tcShift = __builtin_ctz((unsigned)Tc);

    size_t o_xg  = 0;
    size_t o_h0  = o_xg  + (size_t)NB * Tc * NG;
    size_t o_h0s = o_h0  + (size_t)NB * Tc * NH;
    size_t o_c0s = o_h0s + (size_t)NB * NH;
    size_t o_h1s = o_c0s + (size_t)NB * NH;
    size_t o_c1s = o_h1s + (size_t)NB * NH;

    const int M = NB * Tc;
    const int nchunk = NT / Tc;
    for (int c = 0; c < nchunk; ++c) {
        gemm_mfma<1, true><<<dim3(8, M / 128), 256, 0, stream>>>(
            x, w_ih0, b_ih0, b_hh0, ws + o_xg, c * Tc, tcShift);
        recur<true><<<32, 512, 0, stream>>>(
            ws + o_xg, w_hh0, ws + o_h0, ws + o_h0s, ws + o_c0s, Tc, c == 0);
        gemm_mfma<4, false><<<dim3(8, M / 128), 256, 0, stream>>>(
            ws + o_h0, w_ih1, b_ih1, b_hh1, ws + o_xg, 0, 0);
        recur<false><<<32, 512, 0, stream>>>(
            ws + o_xg, w_hh1, nullptr, ws + o_h1s, ws + o_c1s, Tc, c == 0);
    }
    fc_head<<<NB, 64, 0, stream>>>(ws + o_h1s, fc1w, fc1b, fc2w, fc2b, out);
}